// Round 2
// baseline (510.384 us; speedup 1.0000x reference)
//
#include <hip/hip_runtime.h>
#include <type_traits>

typedef __bf16 bf16;
typedef __bf16 bf16x8 __attribute__((ext_vector_type(8)));
typedef float floatx4 __attribute__((ext_vector_type(4)));

#define MFMA_BF16(a, b, c) __builtin_amdgcn_mfma_f32_16x16x32_bf16((a), (b), (c), 0, 0, 0)

// Problem constants: B=4, T=2048, C=1024, H=16, hd=64; M = B*T = 8192
#define SEQ_T 2048
#define DIM_C 1024
#define HDIM 64
#define MROWS 8192
#define N_QKV 3072

// ---------------- transpose fp32 -> bf16: out[N][K] = (bf16)in[K][N] ----------------
__global__ __launch_bounds__(256) void transpose_f32_bf16(
    const float* __restrict__ in, bf16* __restrict__ out, int R, int C) {
  __shared__ bf16 tile[32][33];
  const int bx = blockIdx.x * 32, by = blockIdx.y * 32;
  const int tx = threadIdx.x & 31, ty = threadIdx.x >> 5;
  for (int i = 0; i < 32; i += 8)
    tile[ty + i][tx] = (bf16)in[(size_t)(by + ty + i) * C + bx + tx];
  __syncthreads();
  for (int i = 0; i < 32; i += 8)
    out[(size_t)(bx + ty + i) * R + by + tx] = tile[tx][ty + i];
}

// ---------------- GEMM: Cout[M][N] = A[M][K] @ Bt[N][K]^T + bias ----------------
// 128x128 block tile, BK=32, 4 waves 2x2, each wave 64x64 (4x4 mfma tiles).
// AT = float (cast to bf16 at staging) or bf16. OT = bf16 or float.
template <typename AT, typename OT>
__global__ __launch_bounds__(256) void gemm_bias(
    const AT* __restrict__ A,      // M x K row-major
    const bf16* __restrict__ Bt,   // N x K row-major (B transposed, already bf16)
    const float* __restrict__ bias,// N (fp32)
    OT* __restrict__ Cout,         // M x N row-major
    int M, int N, int K) {
  __shared__ __align__(16) bf16 As[128][40];  // +8 pad
  __shared__ __align__(16) bf16 Bs[128][40];
  const int bm = blockIdx.y * 128, bn = blockIdx.x * 128;
  const int tid = threadIdx.x;
  const int wave = tid >> 6, lane = tid & 63;
  const int wm = (wave >> 1) * 64, wn = (wave & 1) * 64;
  const int quad = lane >> 4, l16 = lane & 15;

  const floatx4 zero = {0.f, 0.f, 0.f, 0.f};
  floatx4 acc[4][4];
  for (int i = 0; i < 4; i++)
    for (int j = 0; j < 4; j++) acc[i][j] = zero;

  for (int k0 = 0; k0 < K; k0 += 32) {
    for (int s = tid; s < 512; s += 256) {
      const int row = s >> 2, k8 = (s & 3) << 3;
      bf16x8 av;
      if constexpr (std::is_same<AT, float>::value) {
        const float4 f0 = *(const float4*)&A[(size_t)(bm + row) * K + k0 + k8];
        const float4 f1 = *(const float4*)&A[(size_t)(bm + row) * K + k0 + k8 + 4];
        av[0] = (bf16)f0.x; av[1] = (bf16)f0.y; av[2] = (bf16)f0.z; av[3] = (bf16)f0.w;
        av[4] = (bf16)f1.x; av[5] = (bf16)f1.y; av[6] = (bf16)f1.z; av[7] = (bf16)f1.w;
      } else {
        av = *(const bf16x8*)&A[(size_t)(bm + row) * K + k0 + k8];
      }
      *(bf16x8*)&As[row][k8] = av;
      *(bf16x8*)&Bs[row][k8] = *(const bf16x8*)&Bt[(size_t)(bn + row) * K + k0 + k8];
    }
    __syncthreads();
    bf16x8 af[4], bfr[4];
    for (int it = 0; it < 4; it++)
      af[it] = *(const bf16x8*)&As[wm + it * 16 + l16][quad * 8];
    for (int jt = 0; jt < 4; jt++)
      bfr[jt] = *(const bf16x8*)&Bs[wn + jt * 16 + l16][quad * 8];
    for (int it = 0; it < 4; it++)
      for (int jt = 0; jt < 4; jt++)
        acc[it][jt] = MFMA_BF16(af[it], bfr[jt], acc[it][jt]);
    __syncthreads();
  }
  // C/D layout: row = quad*4+reg, col = l16 (verified m89)
  for (int jt = 0; jt < 4; jt++) {
    const int col = bn + wn + jt * 16 + l16;
    const float bv = bias[col];
    for (int it = 0; it < 4; it++)
      for (int r = 0; r < 4; r++) {
        const int row = bm + wm + it * 16 + quad * 4 + r;
        Cout[(size_t)row * N + col] = (OT)(acc[it][jt][r] + bv);
      }
  }
}

// ---------------- attention: y[b,t,h*64+d] = sum_{k<=t} exp(-|q-k|^2/16) v ----------------
__global__ __launch_bounds__(256) void attn_kernel(
    const bf16* __restrict__ qkv,  // 8192 x 3072 : [q | k | v]
    bf16* __restrict__ y) {        // 8192 x 1024
  const int qt = blockIdx.x;           // 0..31
  const int bh = blockIdx.y;           // 0..63
  const int bb = bh >> 4, h = bh & 15;
  const int tid = threadIdx.x;
  const int wave = tid >> 6, lane = tid & 63;
  const int quad = lane >> 4, l16 = lane & 15;

  __shared__ __align__(16) bf16 Qs[64][72];
  __shared__ __align__(16) bf16 Ks[64][72];
  __shared__ __align__(16) bf16 Vt[64][72];  // Vt[hd][key]
  __shared__ __align__(16) bf16 Ps[64][72];  // C-layout -> A-layout round-trip
  __shared__ float q2s[64];
  __shared__ float k2s[64];

  const size_t rowbase = (size_t)bb * SEQ_T;
  const float scale = -0.0625f;  // -1/(2*sqrt(64))

  for (int s = tid; s < 512; s += 256) {
    const int r = s >> 3, c8 = (s & 7) << 3;
    *(bf16x8*)&Qs[r][c8] =
        *(const bf16x8*)&qkv[(rowbase + qt * 64 + r) * N_QKV + h * HDIM + c8];
  }
  __syncthreads();
  if (tid < 64) {
    float s = 0.f;
    for (int d = 0; d < 64; d++) { const float v = (float)Qs[tid][d]; s += v * v; }
    q2s[tid] = s;
  }

  const floatx4 zero = {0.f, 0.f, 0.f, 0.f};
  floatx4 accy[4] = {zero, zero, zero, zero};

  for (int kt = 0; kt <= qt; kt++) {
    __syncthreads();  // prior iter's Ps/Vt consumers done; publishes q2s at kt=0
    for (int s = tid; s < 512; s += 256) {
      const int r = s >> 3, c8 = (s & 7) << 3;
      const size_t gr = rowbase + kt * 64 + r;
      *(bf16x8*)&Ks[r][c8] = *(const bf16x8*)&qkv[gr * N_QKV + 1024 + h * HDIM + c8];
      const bf16x8 v = *(const bf16x8*)&qkv[gr * N_QKV + 2048 + h * HDIM + c8];
      for (int j = 0; j < 8; j++) Vt[c8 + j][r] = v[j];
    }
    __syncthreads();
    if (tid < 64) {
      float s = 0.f;
      for (int d = 0; d < 64; d++) { const float v = (float)Ks[tid][d]; s += v * v; }
      k2s[tid] = s;
    }
    floatx4 accs[4] = {zero, zero, zero, zero};
    for (int ks = 0; ks < 2; ks++) {
      const bf16x8 aq = *(const bf16x8*)&Qs[wave * 16 + l16][ks * 32 + quad * 8];
      for (int jt = 0; jt < 4; jt++) {
        const bf16x8 bk = *(const bf16x8*)&Ks[jt * 16 + l16][ks * 32 + quad * 8];
        accs[jt] = MFMA_BF16(aq, bk, accs[jt]);
      }
    }
    __syncthreads();  // k2s ready
    for (int jt = 0; jt < 4; jt++) {
      for (int r = 0; r < 4; r++) {
        const int ml = wave * 16 + quad * 4 + r;
        const int nl = jt * 16 + l16;
        const int gq = qt * 64 + ml, gk = kt * 64 + nl;
        float p = __expf(scale * (q2s[ml] + k2s[nl] - 2.f * accs[jt][r]));
        if (gk > gq) p = 0.f;
        Ps[ml][nl] = (bf16)p;
      }
    }
    __syncthreads();
    for (int ks = 0; ks < 2; ks++) {
      const bf16x8 ap = *(const bf16x8*)&Ps[wave * 16 + l16][ks * 32 + quad * 8];
      for (int jt = 0; jt < 4; jt++) {
        const bf16x8 bv = *(const bf16x8*)&Vt[jt * 16 + l16][ks * 32 + quad * 8];
        accy[jt] = MFMA_BF16(ap, bv, accy[jt]);
      }
    }
  }
  for (int jt = 0; jt < 4; jt++)
    for (int r = 0; r < 4; r++) {
      const int ml = wave * 16 + quad * 4 + r;
      y[(rowbase + qt * 64 + ml) * DIM_C + h * HDIM + jt * 16 + l16] = (bf16)accy[jt][r];
    }
}

extern "C" void kernel_launch(void* const* d_in, const int* in_sizes, int n_in,
                              void* d_out, int out_size, void* d_ws, size_t ws_size,
                              hipStream_t stream) {
  const float* x      = (const float*)d_in[0];  // 8192 x 1024 fp32
  const float* W_attn = (const float*)d_in[1];  // 1024 x 3072 fp32
  const float* b_attn = (const float*)d_in[2];  // 3072 fp32
  const float* W_proj = (const float*)d_in[3];  // 1024 x 1024 fp32
  const float* b_proj = (const float*)d_in[4];  // 1024 fp32
  float* out = (float*)d_out;                   // 8192 x 1024 fp32

  char* ws = (char*)d_ws;
  bf16* qkv = (bf16*)(ws);                    // 50,331,648 B
  bf16* yb  = (bf16*)(ws + 50331648);         // 16,777,216 B
  bf16* WaT = (bf16*)(ws + 67108864);         //  6,291,456 B
  bf16* WpT = (bf16*)(ws + 73400320);         //  2,097,152 B  (total 75,497,472)

  transpose_f32_bf16<<<dim3(96, 32), 256, 0, stream>>>(W_attn, WaT, 1024, 3072);
  transpose_f32_bf16<<<dim3(32, 32), 256, 0, stream>>>(W_proj, WpT, 1024, 1024);
  // qkv = bf16(x) @ bf16(W_attn) + b_attn  (fp32 accum, bf16 store)
  gemm_bias<float, bf16><<<dim3(24, 64), 256, 0, stream>>>(
      x, WaT, b_attn, qkv, MROWS, N_QKV, DIM_C);
  attn_kernel<<<dim3(32, 64), 256, 0, stream>>>(qkv, yb);
  // out = y @ bf16(W_proj) + b_proj  (fp32 accum + fp32 store)
  gemm_bias<bf16, float><<<dim3(8, 64), 256, 0, stream>>>(
      yb, WpT, b_proj, out, MROWS, DIM_C, DIM_C);
}

// Round 3
// 431.072 us; speedup vs baseline: 1.1840x; 1.1840x over previous
//
#include <hip/hip_runtime.h>
#include <type_traits>

typedef __bf16 bf16;
typedef __bf16 bf16x8 __attribute__((ext_vector_type(8)));
typedef float floatx4 __attribute__((ext_vector_type(4)));

#define MFMA_BF16(a, b, c) __builtin_amdgcn_mfma_f32_16x16x32_bf16((a), (b), (c), 0, 0, 0)

// Problem constants: B=4, T=2048, C=1024, H=16, hd=64; M = B*T = 8192
#define SEQ_T 2048
#define DIM_C 1024
#define HDIM 64
#define MROWS 8192
#define N_QKV 3072

// ---------------- transpose fp32 -> bf16: out[N][K] = (bf16)in[K][N] ----------------
__global__ __launch_bounds__(256) void transpose_f32_bf16(
    const float* __restrict__ in, bf16* __restrict__ out, int R, int C) {
  __shared__ bf16 tile[32][33];
  const int bx = blockIdx.x * 32, by = blockIdx.y * 32;
  const int tx = threadIdx.x & 31, ty = threadIdx.x >> 5;
  for (int i = 0; i < 32; i += 8)
    tile[ty + i][tx] = (bf16)in[(size_t)(by + ty + i) * C + bx + tx];
  __syncthreads();
  for (int i = 0; i < 32; i += 8)
    out[(size_t)(bx + ty + i) * R + by + tx] = tile[tx][ty + i];
}

// ---------------- GEMM: Cout[M][N] = A[M][K] @ Bt[N][K]^T + bias ----------------
template <typename AT, typename OT>
__global__ __launch_bounds__(256) void gemm_bias(
    const AT* __restrict__ A,      // M x K row-major
    const bf16* __restrict__ Bt,   // N x K row-major
    const float* __restrict__ bias,// N (fp32)
    OT* __restrict__ Cout,         // M x N row-major
    int M, int N, int K) {
  __shared__ __align__(16) bf16 As[128][40];
  __shared__ __align__(16) bf16 Bs[128][40];
  const int bm = blockIdx.y * 128, bn = blockIdx.x * 128;
  const int tid = threadIdx.x;
  const int wave = tid >> 6, lane = tid & 63;
  const int wm = (wave >> 1) * 64, wn = (wave & 1) * 64;
  const int quad = lane >> 4, l16 = lane & 15;

  const floatx4 zero = {0.f, 0.f, 0.f, 0.f};
  floatx4 acc[4][4];
  for (int i = 0; i < 4; i++)
    for (int j = 0; j < 4; j++) acc[i][j] = zero;

  for (int k0 = 0; k0 < K; k0 += 32) {
    for (int s = tid; s < 512; s += 256) {
      const int row = s >> 2, k8 = (s & 3) << 3;
      bf16x8 av;
      if constexpr (std::is_same<AT, float>::value) {
        const float4 f0 = *(const float4*)&A[(size_t)(bm + row) * K + k0 + k8];
        const float4 f1 = *(const float4*)&A[(size_t)(bm + row) * K + k0 + k8 + 4];
        av[0] = (bf16)f0.x; av[1] = (bf16)f0.y; av[2] = (bf16)f0.z; av[3] = (bf16)f0.w;
        av[4] = (bf16)f1.x; av[5] = (bf16)f1.y; av[6] = (bf16)f1.z; av[7] = (bf16)f1.w;
      } else {
        av = *(const bf16x8*)&A[(size_t)(bm + row) * K + k0 + k8];
      }
      *(bf16x8*)&As[row][k8] = av;
      *(bf16x8*)&Bs[row][k8] = *(const bf16x8*)&Bt[(size_t)(bn + row) * K + k0 + k8];
    }
    __syncthreads();
    bf16x8 af[4], bfr[4];
    for (int it = 0; it < 4; it++)
      af[it] = *(const bf16x8*)&As[wm + it * 16 + l16][quad * 8];
    for (int jt = 0; jt < 4; jt++)
      bfr[jt] = *(const bf16x8*)&Bs[wn + jt * 16 + l16][quad * 8];
    for (int it = 0; it < 4; it++)
      for (int jt = 0; jt < 4; jt++)
        acc[it][jt] = MFMA_BF16(af[it], bfr[jt], acc[it][jt]);
    __syncthreads();
  }
  for (int jt = 0; jt < 4; jt++) {
    const int col = bn + wn + jt * 16 + l16;
    const float bv = bias[col];
    for (int it = 0; it < 4; it++)
      for (int r = 0; r < 4; r++) {
        const int row = bm + wm + it * 16 + quad * 4 + r;
        Cout[(size_t)row * N + col] = (OT)(acc[it][jt][r] + bv);
      }
  }
}

// ---------------- attention ----------------
// Block p handles q-tiles qtA=p and qtB=31-p (paired triangle). 4 waves, each
// owns 16 q-rows of each tile. K/V staged once per kt, consumed by both tiles.
// 2 barriers/iter; Ps round-trip is wave-private (no barrier).
__global__ __launch_bounds__(256, 2) void attn_kernel(
    const bf16* __restrict__ qkv,  // 8192 x 3072 : [q | k | v]
    bf16* __restrict__ y) {        // 8192 x 1024
  const int p = blockIdx.x;            // 0..15  (p=0 = most work, dispatched first)
  const int bh = blockIdx.y;           // 0..63
  const int bb = bh >> 4, h = bh & 15;
  const int qtA = p, qtB = 31 - p;
  const int tid = threadIdx.x;
  const int wave = tid >> 6, lane = tid & 63;
  const int quad = lane >> 4, l16 = lane & 15;

  __shared__ __align__(16) bf16 Qs[128][72];   // rows 0..63 tile A, 64..127 tile B
  __shared__ __align__(16) bf16 Ps[128][72];
  __shared__ __align__(16) bf16 Ks[64][72];
  __shared__ __align__(16) bf16 Vt[64][72];    // [d][key ^ (d & 0x38)] swizzled
  __shared__ float q2c[128];                   // q2 * c2
  __shared__ float k2c[64];                    // k2 * c2

  const size_t rowbase = (size_t)bb * SEQ_T;
  const float c2 = -0.09016844f;    // -1/16 * log2(e)
  const float m2c2 = 0.18033688f;   // -2*c2

  // ---- stage Q (both tiles) + q2c: partials from registers + shfl_xor ----
  {
    const int r0 = tid >> 3, c8 = (tid & 7) << 3;
    for (int i = 0; i < 4; i++) {
      const int r = r0 + i * 32;
      const int gq = (r < 64) ? (qtA * 64 + r) : (qtB * 64 + (r - 64));
      const bf16x8 v = *(const bf16x8*)&qkv[(rowbase + gq) * N_QKV + h * HDIM + c8];
      *(bf16x8*)&Qs[r][c8] = v;
      float s = 0.f;
      for (int j = 0; j < 8; j++) { const float f = (float)v[j]; s += f * f; }
      s += __shfl_xor(s, 1); s += __shfl_xor(s, 2); s += __shfl_xor(s, 4);
      if ((tid & 7) == 0) q2c[r] = s * c2;
    }
  }

  const floatx4 zero = {0.f, 0.f, 0.f, 0.f};
  floatx4 accy[2][4];
  for (int T = 0; T < 2; T++)
    for (int jt = 0; jt < 4; jt++) accy[T][jt] = zero;

  for (int kt = 0; kt <= qtB; kt++) {
    const bool actA = (kt <= qtA);
    // ---- stage K row-major, V transposed+swizzled, k2c from registers ----
    {
      const int r0 = tid >> 3, c8 = (tid & 7) << 3;
      for (int i = 0; i < 2; i++) {
        const int r = r0 + i * 32;
        const size_t gr = rowbase + (size_t)(kt * 64 + r);
        const bf16x8 kv = *(const bf16x8*)&qkv[gr * N_QKV + 1024 + h * HDIM + c8];
        *(bf16x8*)&Ks[r][c8] = kv;
        float s = 0.f;
        for (int j = 0; j < 8; j++) { const float f = (float)kv[j]; s += f * f; }
        s += __shfl_xor(s, 1); s += __shfl_xor(s, 2); s += __shfl_xor(s, 4);
        if ((tid & 7) == 0) k2c[r] = s * c2;
        const bf16x8 vv = *(const bf16x8*)&qkv[gr * N_QKV + 2048 + h * HDIM + c8];
        for (int j = 0; j < 8; j++) Vt[c8 + j][r ^ c8] = vv[j];  // 2-way banks
      }
    }
    __syncthreads();  // staging + k2c visible (also publishes Qs/q2c at kt=0)

    // ---- S = Q.K^T ----
    bf16x8 bk[4][2];
    for (int jt = 0; jt < 4; jt++)
      for (int ks = 0; ks < 2; ks++)
        bk[jt][ks] = *(const bf16x8*)&Ks[jt * 16 + l16][ks * 32 + quad * 8];
    floatx4 accs[2][4];
    for (int T = 0; T < 2; T++)
      for (int jt = 0; jt < 4; jt++) accs[T][jt] = zero;
    for (int T = 0; T < 2; T++) {
      if (T == 0 && !actA) continue;
      for (int ks = 0; ks < 2; ks++) {
        const bf16x8 aq =
            *(const bf16x8*)&Qs[T * 64 + wave * 16 + l16][ks * 32 + quad * 8];
        for (int jt = 0; jt < 4; jt++)
          accs[T][jt] = MFMA_BF16(aq, bk[jt][ks], accs[T][jt]);
      }
    }

    // ---- P = exp2(c2*(q2+k2) + (-2 c2)*qk), mask only on diagonal tile ----
    for (int T = 0; T < 2; T++) {
      if (T == 0 && !actA) continue;
      const bool diag = (kt == (T == 0 ? qtA : qtB));
      for (int jt = 0; jt < 4; jt++) {
        const int nl = jt * 16 + l16;
        const float kc = k2c[nl];
        for (int r = 0; r < 4; r++) {
          const int ml = wave * 16 + quad * 4 + r;
          float pe = exp2f(fmaf(m2c2, accs[T][jt][r], q2c[T * 64 + ml] + kc));
          if (diag && nl > ml) pe = 0.f;
          Ps[T * 64 + ml][nl] = (bf16)pe;  // wave-private rows
        }
      }
    }

    // ---- y += P.V ----
    bf16x8 bv[4][2];
    for (int jt = 0; jt < 4; jt++)
      for (int ks = 0; ks < 2; ks++) {
        const int d = jt * 16 + l16;
        bv[jt][ks] = *(const bf16x8*)&Vt[d][(ks * 32 + quad * 8) ^ (d & 0x38)];
      }
    for (int T = 0; T < 2; T++) {
      if (T == 0 && !actA) continue;
      for (int ks = 0; ks < 2; ks++) {
        const bf16x8 ap =
            *(const bf16x8*)&Ps[T * 64 + wave * 16 + l16][ks * 32 + quad * 8];
        for (int jt = 0; jt < 4; jt++)
          accy[T][jt] = MFMA_BF16(ap, bv[jt][ks], accy[T][jt]);
      }
    }
    __syncthreads();  // all Ks/Vt reads done before next staging
  }

  // ---- epilogue ----
  for (int T = 0; T < 2; T++) {
    const int qt = (T == 0) ? qtA : qtB;
    for (int jt = 0; jt < 4; jt++) {
      const int col = h * HDIM + jt * 16 + l16;
      for (int r = 0; r < 4; r++) {
        const int ml = wave * 16 + quad * 4 + r;
        y[(rowbase + qt * 64 + ml) * DIM_C + col] = (bf16)accy[T][jt][r];
      }
    }
  }
}

extern "C" void kernel_launch(void* const* d_in, const int* in_sizes, int n_in,
                              void* d_out, int out_size, void* d_ws, size_t ws_size,
                              hipStream_t stream) {
  const float* x      = (const float*)d_in[0];  // 8192 x 1024 fp32
  const float* W_attn = (const float*)d_in[1];  // 1024 x 3072 fp32
  const float* b_attn = (const float*)d_in[2];  // 3072 fp32
  const float* W_proj = (const float*)d_in[3];  // 1024 x 1024 fp32
  const float* b_proj = (const float*)d_in[4];  // 1024 fp32
  float* out = (float*)d_out;                   // 8192 x 1024 fp32

  char* ws = (char*)d_ws;
  bf16* qkv = (bf16*)(ws);                    // 50,331,648 B
  bf16* yb  = (bf16*)(ws + 50331648);         // 16,777,216 B
  bf16* WaT = (bf16*)(ws + 67108864);         //  6,291,456 B
  bf16* WpT = (bf16*)(ws + 73400320);         //  2,097,152 B  (total 75,497,472)

  transpose_f32_bf16<<<dim3(96, 32), 256, 0, stream>>>(W_attn, WaT, 1024, 3072);
  transpose_f32_bf16<<<dim3(32, 32), 256, 0, stream>>>(W_proj, WpT, 1024, 1024);
  gemm_bias<float, bf16><<<dim3(24, 64), 256, 0, stream>>>(
      x, WaT, b_attn, qkv, MROWS, N_QKV, DIM_C);
  attn_kernel<<<dim3(16, 64), 256, 0, stream>>>(qkv, yb);
  gemm_bias<bf16, float><<<dim3(8, 64), 256, 0, stream>>>(
      yb, WpT, b_proj, out, MROWS, DIM_C, DIM_C);
}

// Round 4
// 310.212 us; speedup vs baseline: 1.6453x; 1.3896x over previous
//
#include <hip/hip_runtime.h>

typedef __bf16 bf16;
typedef __bf16 bf16x8 __attribute__((ext_vector_type(8)));
typedef float floatx4 __attribute__((ext_vector_type(4)));

#define MFMA_BF16(a, b, c) __builtin_amdgcn_mfma_f32_16x16x32_bf16((a), (b), (c), 0, 0, 0)

// async global->LDS, 16B per lane; LDS dest = wave-uniform base + lane*16
#define GLOAD_LDS16(gp, lp)                                      \
  __builtin_amdgcn_global_load_lds(                              \
      (const __attribute__((address_space(1))) void*)(gp),       \
      (__attribute__((address_space(3))) void*)(lp), 16, 0, 0)

// Problem constants: B=4, T=2048, C=1024, H=16, hd=64; M = B*T = 8192
#define SEQ_T 2048
#define DIM_C 1024
#define HDIM 64
#define MROWS 8192
#define N_QKV 3072

// ---------------- x fp32 -> bf16 ----------------
__global__ __launch_bounds__(256) void f32_to_bf16(
    const float* __restrict__ in, bf16* __restrict__ out) {
  const size_t i = ((size_t)blockIdx.x * 256 + threadIdx.x) * 8;
  const float4 f0 = *(const float4*)&in[i];
  const float4 f1 = *(const float4*)&in[i + 4];
  bf16x8 v;
  v[0] = (bf16)f0.x; v[1] = (bf16)f0.y; v[2] = (bf16)f0.z; v[3] = (bf16)f0.w;
  v[4] = (bf16)f1.x; v[5] = (bf16)f1.y; v[6] = (bf16)f1.z; v[7] = (bf16)f1.w;
  *(bf16x8*)&out[i] = v;
}

// ---------------- transpose fp32 -> bf16: out[N][K] = (bf16)in[K][N] ----------------
__global__ __launch_bounds__(256) void transpose_f32_bf16(
    const float* __restrict__ in, bf16* __restrict__ out, int R, int C) {
  __shared__ bf16 tile[32][33];
  const int bx = blockIdx.x * 32, by = blockIdx.y * 32;
  const int tx = threadIdx.x & 31, ty = threadIdx.x >> 5;
  for (int i = 0; i < 32; i += 8)
    tile[ty + i][tx] = (bf16)in[(size_t)(by + ty + i) * C + bx + tx];
  __syncthreads();
  for (int i = 0; i < 32; i += 8)
    out[(size_t)(bx + ty + i) * R + by + tx] = tile[tx][ty + i];
}

// ---------------- GEMM (m97 structure): Cout = A[M][K] @ Bt[N][K]^T + bias ----------------
// 128x128 tile, BK=32, global_load_lds width-16 staging, XOR-4 block swizzle.
template <typename OT>
__global__ __launch_bounds__(256) void gemm_lds(
    const bf16* __restrict__ A,     // M x K row-major (bf16)
    const bf16* __restrict__ Bt,    // N x K row-major (bf16)
    const float* __restrict__ bias, // N (fp32)
    OT* __restrict__ Cout,          // M x N row-major
    int M, int N, int K) {
  __shared__ __align__(16) bf16 Asl[128 * 32];  // seg s: row=s>>2, phys block=s&3
  __shared__ __align__(16) bf16 Bsl[128 * 32];  // content block = (s&3) ^ (row&3)
  const int bm = blockIdx.y * 128, bn = blockIdx.x * 128;
  const int tid = threadIdx.x;
  const int wave = tid >> 6, lane = tid & 63;
  const int wm = (wave >> 1) * 64, wn = (wave & 1) * 64;
  const int quad = lane >> 4, l16 = lane & 15;

  const floatx4 zero = {0.f, 0.f, 0.f, 0.f};
  floatx4 acc[4][4];
  for (int i = 0; i < 4; i++)
    for (int j = 0; j < 4; j++) acc[i][j] = zero;

  // per-lane global pointers for the two staging instructions (segs tid, 256+tid)
  const int s0 = tid, s1 = 256 + tid;
  const int r0 = s0 >> 2, lb0 = (s0 & 3) ^ (r0 & 3);
  const int r1 = s1 >> 2, lb1 = (s1 & 3) ^ (r1 & 3);
  const bf16* ga0 = &A[(size_t)(bm + r0) * K + lb0 * 8];
  const bf16* ga1 = &A[(size_t)(bm + r1) * K + lb1 * 8];
  const bf16* gb0 = &Bt[(size_t)(bn + r0) * K + lb0 * 8];
  const bf16* gb1 = &Bt[(size_t)(bn + r1) * K + lb1 * 8];
  bf16* lds0 = &Asl[(wave * 64) * 8];          // wave-uniform bases
  bf16* lds1 = &Asl[(256 + wave * 64) * 8];
  bf16* ldsB0 = &Bsl[(wave * 64) * 8];
  bf16* ldsB1 = &Bsl[(256 + wave * 64) * 8];

  for (int k0 = 0; k0 < K; k0 += 32) {
    GLOAD_LDS16(ga0 + k0, lds0);
    GLOAD_LDS16(ga1 + k0, lds1);
    GLOAD_LDS16(gb0 + k0, ldsB0);
    GLOAD_LDS16(gb1 + k0, ldsB1);
    __syncthreads();
    bf16x8 af[4], bfr[4];
    for (int it = 0; it < 4; it++) {
      const int row = wm + it * 16 + l16;
      af[it] = *(const bf16x8*)&Asl[(row * 4 + (quad ^ (row & 3))) * 8];
    }
    for (int jt = 0; jt < 4; jt++) {
      const int row = wn + jt * 16 + l16;
      bfr[jt] = *(const bf16x8*)&Bsl[(row * 4 + (quad ^ (row & 3))) * 8];
    }
    for (int it = 0; it < 4; it++)
      for (int jt = 0; jt < 4; jt++)
        acc[it][jt] = MFMA_BF16(af[it], bfr[jt], acc[it][jt]);
    __syncthreads();
  }
  // C/D layout: row = quad*4+reg, col = l16
  for (int jt = 0; jt < 4; jt++) {
    const int col = bn + wn + jt * 16 + l16;
    const float bv = bias[col];
    for (int it = 0; it < 4; it++)
      for (int r = 0; r < 4; r++) {
        const int row = bm + wm + it * 16 + quad * 4 + r;
        Cout[(size_t)row * N + col] = (OT)(acc[it][jt][r] + bv);
      }
  }
}

// ---------------- attention ----------------
// Block p: q-tiles qtA=p, qtB=31-p (paired triangle, uniform work). Q frags in
// registers (wave-private rows); exp factored: P̂=2^(m2c2·qk), V rows pre-scaled
// by 2^(c2·k2), epilogue scaled by 2^(c2·q2). LDS 37.5 KB -> 4 blocks/CU.
__global__ __launch_bounds__(256, 4) void attn_kernel(
    const bf16* __restrict__ qkv,  // 8192 x 3072 : [q | k | v]
    bf16* __restrict__ y) {        // 8192 x 1024
  const int p = blockIdx.x;            // 0..15
  const int bh = blockIdx.y;           // 0..63
  const int bb = bh >> 4, h = bh & 15;
  const int qtA = p, qtB = 31 - p;
  const int tid = threadIdx.x;
  const int wave = tid >> 6, lane = tid & 63;
  const int quad = lane >> 4, l16 = lane & 15;

  __shared__ __align__(16) bf16 Ps[128][72];   // rows 0..63 tile A, 64..127 tile B
  __shared__ __align__(16) bf16 Ks[64][72];
  __shared__ __align__(16) bf16 Vt[64][72];    // [d][key ^ (d & 0x38)], k2-scaled
  __shared__ float q2c[128];                   // c2 * |q|^2 per q-row

  const size_t rowbase = (size_t)bb * SEQ_T;
  const float c2 = -0.09016844f;    // -1/16 * log2(e)
  const float m2c2 = 0.18033688f;   // -2*c2

  // ---- Q fragments in registers + q2c (shfl across quads) ----
  bf16x8 aq[2][2];
  for (int T = 0; T < 2; T++) {
    const int qt = T ? qtB : qtA;
    const size_t grow = rowbase + qt * 64 + wave * 16 + l16;
    float s = 0.f;
    for (int ks = 0; ks < 2; ks++) {
      aq[T][ks] = *(const bf16x8*)&qkv[grow * N_QKV + h * HDIM + ks * 32 + quad * 8];
      for (int j = 0; j < 8; j++) { const float f = (float)aq[T][ks][j]; s += f * f; }
    }
    s += __shfl_xor(s, 16); s += __shfl_xor(s, 32);
    if (quad == 0) q2c[T * 64 + wave * 16 + l16] = s * c2;
  }

  const floatx4 zero = {0.f, 0.f, 0.f, 0.f};
  floatx4 accy[2][4];
  for (int T = 0; T < 2; T++)
    for (int jt = 0; jt < 4; jt++) accy[T][jt] = zero;

  for (int kt = 0; kt <= qtB; kt++) {
    const bool actA = (kt <= qtA);
    // ---- stage K row-major; V transposed+swizzled, scaled by 2^(c2*k2) ----
    {
      const int r0 = tid >> 3, c8 = (tid & 7) << 3;
      for (int i = 0; i < 2; i++) {
        const int r = r0 + i * 32;
        const size_t gr = rowbase + (size_t)(kt * 64 + r);
        const bf16x8 kv = *(const bf16x8*)&qkv[gr * N_QKV + 1024 + h * HDIM + c8];
        *(bf16x8*)&Ks[r][c8] = kv;
        float s = 0.f;
        for (int j = 0; j < 8; j++) { const float f = (float)kv[j]; s += f * f; }
        s += __shfl_xor(s, 1); s += __shfl_xor(s, 2); s += __shfl_xor(s, 4);
        const float vscale = exp2f(s * c2);
        const bf16x8 vv = *(const bf16x8*)&qkv[gr * N_QKV + 2048 + h * HDIM + c8];
        for (int j = 0; j < 8; j++)
          Vt[c8 + j][r ^ c8] = (bf16)((float)vv[j] * vscale);
      }
    }
    __syncthreads();  // staging visible (also publishes q2c at kt=0)

    // ---- S = Q.K^T ----
    bf16x8 bk[4][2];
    for (int jt = 0; jt < 4; jt++)
      for (int ks = 0; ks < 2; ks++)
        bk[jt][ks] = *(const bf16x8*)&Ks[jt * 16 + l16][ks * 32 + quad * 8];
    floatx4 accs[2][4];
    for (int T = 0; T < 2; T++)
      for (int jt = 0; jt < 4; jt++) accs[T][jt] = zero;
    for (int T = 0; T < 2; T++) {
      if (T == 0 && !actA) continue;
      for (int ks = 0; ks < 2; ks++)
        for (int jt = 0; jt < 4; jt++)
          accs[T][jt] = MFMA_BF16(aq[T][ks], bk[jt][ks], accs[T][jt]);
    }

    // ---- P̂ = 2^(m2c2*qk), mask on diagonal tile; wave-private Ps rows ----
    for (int T = 0; T < 2; T++) {
      if (T == 0 && !actA) continue;
      const bool diag = (kt == (T == 0 ? qtA : qtB));
      for (int jt = 0; jt < 4; jt++) {
        const int nl = jt * 16 + l16;
        for (int r = 0; r < 4; r++) {
          const int ml = wave * 16 + quad * 4 + r;
          float pe = exp2f(m2c2 * accs[T][jt][r]);
          if (diag && nl > ml) pe = 0.f;
          Ps[T * 64 + ml][nl] = (bf16)pe;
        }
      }
    }

    // ---- y += P̂ . Ṽ ----
    for (int T = 0; T < 2; T++) {
      if (T == 0 && !actA) continue;
      for (int ks = 0; ks < 2; ks++) {
        const bf16x8 ap =
            *(const bf16x8*)&Ps[T * 64 + wave * 16 + l16][ks * 32 + quad * 8];
        for (int jt = 0; jt < 4; jt++) {
          const int d = jt * 16 + l16;
          const bf16x8 bv =
              *(const bf16x8*)&Vt[d][(ks * 32 + quad * 8) ^ (d & 0x38)];
          accy[T][jt] = MFMA_BF16(ap, bv, accy[T][jt]);
        }
      }
    }
    __syncthreads();  // Ks/Vt reads done before next staging
  }

  // ---- epilogue: scale by 2^(c2*q2), store ----
  for (int T = 0; T < 2; T++) {
    const int qt = (T == 0) ? qtA : qtB;
    float ysc[4];
    for (int r = 0; r < 4; r++)
      ysc[r] = exp2f(q2c[T * 64 + wave * 16 + quad * 4 + r]);
    for (int jt = 0; jt < 4; jt++) {
      const int col = h * HDIM + jt * 16 + l16;
      for (int r = 0; r < 4; r++) {
        const int ml = wave * 16 + quad * 4 + r;
        y[(rowbase + qt * 64 + ml) * DIM_C + col] = (bf16)(accy[T][jt][r] * ysc[r]);
      }
    }
  }
}

extern "C" void kernel_launch(void* const* d_in, const int* in_sizes, int n_in,
                              void* d_out, int out_size, void* d_ws, size_t ws_size,
                              hipStream_t stream) {
  const float* x      = (const float*)d_in[0];  // 8192 x 1024 fp32
  const float* W_attn = (const float*)d_in[1];  // 1024 x 3072 fp32
  const float* b_attn = (const float*)d_in[2];  // 3072 fp32
  const float* W_proj = (const float*)d_in[3];  // 1024 x 1024 fp32
  const float* b_proj = (const float*)d_in[4];  // 1024 fp32
  float* out = (float*)d_out;                   // 8192 x 1024 fp32

  char* ws = (char*)d_ws;
  bf16* qkv = (bf16*)(ws);             // 50,331,648 B
  bf16* yb  = (bf16*)(ws + 50331648);  // 16,777,216 B — also holds xb before attn
  bf16* WaT = (bf16*)(ws + 67108864);  //  6,291,456 B
  bf16* WpT = (bf16*)(ws + 73400320);  //  2,097,152 B  (total 75,497,472)
  bf16* xb  = yb;                      // x-bf16 is dead before attn writes yb

  f32_to_bf16<<<dim3(4096), 256, 0, stream>>>(x, xb);
  transpose_f32_bf16<<<dim3(96, 32), 256, 0, stream>>>(W_attn, WaT, 1024, 3072);
  transpose_f32_bf16<<<dim3(32, 32), 256, 0, stream>>>(W_proj, WpT, 1024, 1024);
  gemm_lds<bf16><<<dim3(24, 64), 256, 0, stream>>>(
      xb, WaT, b_attn, qkv, MROWS, N_QKV, DIM_C);
  attn_kernel<<<dim3(16, 64), 256, 0, stream>>>(qkv, yb);
  gemm_lds<float><<<dim3(8, 64), 256, 0, stream>>>(
      yb, WpT, b_proj, out, MROWS, DIM_C, DIM_C);
}